// Round 2
// baseline (934.059 us; speedup 1.0000x reference)
//
#include <hip/hip_runtime.h>
#include <stdint.h>

#define EPS_VAL 2.220446049250313e-16f

typedef unsigned short u16;
typedef __bf16 bf16x8 __attribute__((ext_vector_type(8)));
typedef float f32x4 __attribute__((ext_vector_type(4)));

static __device__ __forceinline__ u16 f2bf(float v) {
    __bf16 b = (__bf16)v;
    return __builtin_bit_cast(u16, b);
}
static __device__ __forceinline__ float bf2f(u16 u) {
    __bf16 b = __builtin_bit_cast(__bf16, u);
    return (float)b;
}

// ---------------- transpose + convert: in [R][C] f32 -> out [C][R] bf16 ----------------
__global__ void k_transpose_cvt(const float* __restrict__ in, u16* __restrict__ out,
                                int R, int C) {
    __shared__ float t[32][33];
    const float* ip = in + (size_t)blockIdx.z * R * C;
    u16* op = out + (size_t)blockIdx.z * R * C;
    int tx = threadIdx.x & 31, ty = threadIdx.x >> 5;   // ty 0..7
    int c = blockIdx.x * 32 + tx;
    #pragma unroll
    for (int i = 0; i < 4; ++i) {
        int r = blockIdx.y * 32 + ty + i * 8;
        t[ty + i * 8][tx] = ip[(size_t)r * C + c];
    }
    __syncthreads();
    int r2 = blockIdx.y * 32 + tx;                      // output col = original row
    #pragma unroll
    for (int i = 0; i < 4; ++i) {
        int c2 = blockIdx.x * 32 + ty + i * 8;          // output row = original col
        op[(size_t)c2 * R + r2] = f2bf(t[tx][ty + i * 8]);
    }
}

// ------- gating (fused x->bf16): logits, top-2, softmax, expert lists, xb -------
__global__ void k_gate(const float* __restrict__ x, const float* __restrict__ wg,
                       u16* __restrict__ xb, int* __restrict__ cnt,
                       uint2* __restrict__ asg, float4* __restrict__ rec) {
    int row  = blockIdx.x * 4 + (threadIdx.x >> 6);
    int lane = threadIdx.x & 63;
    // each lane owns d = lane*8 .. lane*8+7
    const float4* px = (const float4*)(x + (size_t)row * 512) + lane * 2;
    float4 v0 = px[0], v1 = px[1];
    union { u16 h[8]; uint4 u; } o;
    o.h[0]=f2bf(v0.x); o.h[1]=f2bf(v0.y); o.h[2]=f2bf(v0.z); o.h[3]=f2bf(v0.w);
    o.h[4]=f2bf(v1.x); o.h[5]=f2bf(v1.y); o.h[6]=f2bf(v1.z); o.h[7]=f2bf(v1.w);
    ((uint4*)(xb + (size_t)row * 512))[lane] = o.u;

    float xv[8] = {v0.x, v0.y, v0.z, v0.w, v1.x, v1.y, v1.z, v1.w};
    float a0=0,a1=0,a2=0,a3=0,a4=0,a5=0,a6=0,a7=0;
    const float4* wp = (const float4*)wg + (size_t)lane * 16;   // 64 floats contiguous/lane
    #pragma unroll
    for (int j = 0; j < 8; ++j) {
        float4 wa = wp[j * 2], wb = wp[j * 2 + 1];
        float v = xv[j];
        a0 += v*wa.x; a1 += v*wa.y; a2 += v*wa.z; a3 += v*wa.w;
        a4 += v*wb.x; a5 += v*wb.y; a6 += v*wb.z; a7 += v*wb.w;
    }
    #pragma unroll
    for (int off = 32; off; off >>= 1) {
        a0 += __shfl_xor(a0, off); a1 += __shfl_xor(a1, off);
        a2 += __shfl_xor(a2, off); a3 += __shfl_xor(a3, off);
        a4 += __shfl_xor(a4, off); a5 += __shfl_xor(a5, off);
        a6 += __shfl_xor(a6, off); a7 += __shfl_xor(a7, off);
    }
    if (lane == 0) {
        float v[8] = {a0,a1,a2,a3,a4,a5,a6,a7};
        int i0 = 0;
        #pragma unroll
        for (int e = 1; e < 8; ++e) if (v[e] > v[i0]) i0 = e;   // lowest idx wins ties
        int i1 = (i0 == 0) ? 1 : 0;
        #pragma unroll
        for (int e = 0; e < 8; ++e) if (e != i0 && v[e] > v[i1]) i1 = e;
        float ex = expf(v[i1] - v[i0]);
        float g0 = 1.f / (1.f + ex), g1 = ex / (1.f + ex);
        rec[row] = make_float4(__int_as_float(i0), __int_as_float(i1), g0, g1);
        if (i0 != 7) {
            int p = atomicAdd(&cnt[i0], 1);
            asg[i0 * 16384 + p] = make_uint2((unsigned)(row << 1), __float_as_uint(g0));
        }
        if (i1 != 7) {
            int p = atomicAdd(&cnt[i1], 1);
            asg[i1 * 16384 + p] = make_uint2((unsigned)((row << 1) | 1), __float_as_uint(g1));
        }
    }
}

// ------- fused per-expert MLP, 16 waves, BM=64, h-chunk=64, Xs aliased with W1s -------
__global__ __launch_bounds__(1024) void k_expert(
    const u16* __restrict__ xb,    // [N][512] bf16
    const u16* __restrict__ w1t,   // [7][2048][512] bf16 (W1^T)
    const u16* __restrict__ w2t,   // [7][512][2048] bf16 (W2^T)
    const float* __restrict__ b1,  // [7][2048]
    const float* __restrict__ b2,  // [7][512]
    const int* __restrict__ cnt,
    const uint2* __restrict__ asg, // [7][N]
    u16* __restrict__ ybuf)        // [2][N][512] bf16
{
    // smem: [0,66560) = Xs[64][520] aliased with W1s[64][520]
    //       [66560,140288) = W2s[512][72]; [140288,149504) = Hs[64][72]
    __shared__ __attribute__((aligned(16))) char smem[149504];
    u16 (*Xs)[520]  = (u16 (*)[520])smem;
    u16 (*W1s)[520] = (u16 (*)[520])smem;
    u16 (*W2s)[72]  = (u16 (*)[72])(smem + 66560);
    u16 (*Hs)[72]   = (u16 (*)[72])(smem + 140288);
    __shared__ int   rsl[64];
    __shared__ float gl[64];

    const int e    = blockIdx.y;
    const int base = blockIdx.x * 64;
    const int ce   = cnt[e];
    if (base >= ce) return;

    const int tid = threadIdx.x;
    if (tid < 64) {
        int idx = base + tid;
        if (idx < ce) {
            uint2 a = asg[e * 16384 + idx];
            rsl[tid] = (int)a.x;
            gl[tid]  = __builtin_bit_cast(float, a.y);
        } else { rsl[tid] = -1; gl[tid] = 0.f; }
    }
    __syncthreads();

    // stage X rows (64 x 512 bf16)
    #pragma unroll
    for (int it = 0; it < 4; ++it) {
        int i = it * 1024 + tid;
        int r = i >> 6, c = i & 63;
        int rs = rsl[r];
        int grow = (rs < 0) ? 0 : (rs >> 1);
        uint4 v = *(const uint4*)(xb + (size_t)grow * 512 + c * 8);
        *(uint4*)&Xs[r][c * 8] = v;
    }
    __syncthreads();

    const int w    = tid >> 6;            // wave 0..15
    const int lane = tid & 63;
    const int l16  = lane & 15;
    const int q    = lane >> 4;           // 0..3
    const int kb   = q * 8;
    const int rt   = (w >> 2) * 16;       // row group (4 groups)
    const int b    = w & 3;               // col group (4 groups)
    const int hb   = b * 16;              // phase-1 local h sub-tile

    bf16x8 xa[16];
    #pragma unroll
    for (int kk = 0; kk < 16; ++kk)
        xa[kk] = *(const bf16x8*)&Xs[rt + l16][kk * 32 + kb];
    __syncthreads();   // all xa reads done before W1s overwrites Xs

    f32x4 acc[8];
    #pragma unroll
    for (int nt = 0; nt < 8; ++nt) acc[nt] = (f32x4){0.f, 0.f, 0.f, 0.f};

    const u16* w1p = w1t + (size_t)e * 2048 * 512;
    const u16* w2p = w2t + (size_t)e * 512 * 2048;

    for (int hc = 0; hc < 2048; hc += 64) {
        // stage W1^T chunk: 64 (h) x 512 (k), contiguous
        #pragma unroll
        for (int it = 0; it < 4; ++it) {
            int i = it * 1024 + tid;
            int r = i >> 6, c = i & 63;
            uint4 v = *(const uint4*)(w1p + (size_t)(hc + r) * 512 + c * 8);
            *(uint4*)&W1s[r][c * 8] = v;
        }
        // stage W2^T chunk: 512 (d) x 64 (h)
        #pragma unroll
        for (int it = 0; it < 4; ++it) {
            int i = it * 1024 + tid;
            int d = i >> 3, p = i & 7;
            uint4 v = *(const uint4*)(w2p + (size_t)d * 2048 + hc + p * 8);
            *(uint4*)&W2s[d][p * 8] = v;
        }
        __syncthreads();

        // phase 1: H tile rows rt..rt+16, local h cols hb..hb+16, K=512 (2 chains)
        f32x4 h0 = (f32x4){0.f,0.f,0.f,0.f}, h1 = (f32x4){0.f,0.f,0.f,0.f};
        #pragma unroll
        for (int kk = 0; kk < 16; kk += 2) {
            bf16x8 bf0 = *(const bf16x8*)&W1s[hb + l16][kk * 32 + kb];
            bf16x8 bf1 = *(const bf16x8*)&W1s[hb + l16][(kk + 1) * 32 + kb];
            h0 = __builtin_amdgcn_mfma_f32_16x16x32_bf16(xa[kk],     bf0, h0, 0, 0, 0);
            h1 = __builtin_amdgcn_mfma_f32_16x16x32_bf16(xa[kk + 1], bf1, h1, 0, 0, 0);
        }
        float bias = b1[e * 2048 + hc + hb + l16];
        #pragma unroll
        for (int r = 0; r < 4; ++r) {
            float v = h0[r] + h1[r] + bias;
            v = v > 0.f ? v : 0.f;
            Hs[rt + q * 4 + r][hb + l16] = f2bf(v);
        }
        __syncthreads();

        // phase 2: acc += Hs(rows rt, k=64) @ W2s(cols b*128..+128)
        bf16x8 af0 = *(const bf16x8*)&Hs[rt + l16][kb];
        bf16x8 af1 = *(const bf16x8*)&Hs[rt + l16][32 + kb];
        #pragma unroll
        for (int nt = 0; nt < 8; ++nt) {
            bf16x8 bm0 = *(const bf16x8*)&W2s[b * 128 + nt * 16 + l16][kb];
            bf16x8 bm1 = *(const bf16x8*)&W2s[b * 128 + nt * 16 + l16][32 + kb];
            acc[nt] = __builtin_amdgcn_mfma_f32_16x16x32_bf16(af0, bm0, acc[nt], 0, 0, 0);
            acc[nt] = __builtin_amdgcn_mfma_f32_16x16x32_bf16(af1, bm1, acc[nt], 0, 0, 0);
        }
        __syncthreads();
    }

    // epilogue: ybuf[slot][row][d] = bf16(g * (acc + b2))
    #pragma unroll
    for (int nt = 0; nt < 8; ++nt) {
        int d = b * 128 + nt * 16 + l16;
        float b2v = b2[e * 512 + d];
        #pragma unroll
        for (int r = 0; r < 4; ++r) {
            int m = rt + q * 4 + r;
            int rs = rsl[m];
            if (rs >= 0) {
                int grow = rs >> 1, slot = rs & 1;
                ybuf[((size_t)slot * 16384 + grow) * 512 + d] =
                    f2bf(gl[m] * (acc[nt][r] + b2v));
            }
        }
    }
}

// ---------------- final combine + EPS replacement ----------------
__global__ void k_final(const float* __restrict__ x, const float4* __restrict__ rec,
                        const u16* __restrict__ ybuf, float* __restrict__ out) {
    int i = blockIdx.x * 256 + threadIdx.x;     // one float4; total 16384*128
    int row = i >> 7;
    float4 r = rec[row];
    int e0 = __float_as_int(r.x), e1 = __float_as_int(r.y);
    float g7 = (e0 == 7) ? r.z : ((e1 == 7) ? r.w : 0.f);
    float4 xv = ((const float4*)x)[i];
    float o0 = g7 * xv.x, o1 = g7 * xv.y, o2 = g7 * xv.z, o3 = g7 * xv.w;
    size_t off = (size_t)i * 4;
    if (e0 != 7) {
        uint2 y = *(const uint2*)(ybuf + off);
        o0 += bf2f((u16)(y.x & 0xffff)); o1 += bf2f((u16)(y.x >> 16));
        o2 += bf2f((u16)(y.y & 0xffff)); o3 += bf2f((u16)(y.y >> 16));
    }
    if (e1 != 7) {
        uint2 y = *(const uint2*)(ybuf + 8388608 + off);
        o0 += bf2f((u16)(y.x & 0xffff)); o1 += bf2f((u16)(y.x >> 16));
        o2 += bf2f((u16)(y.y & 0xffff)); o3 += bf2f((u16)(y.y >> 16));
    }
    float4 res;
    res.x = (o0 == 0.f) ? EPS_VAL : o0;
    res.y = (o1 == 0.f) ? EPS_VAL : o1;
    res.z = (o2 == 0.f) ? EPS_VAL : o2;
    res.w = (o3 == 0.f) ? EPS_VAL : o3;
    ((float4*)out)[i] = res;
}

extern "C" void kernel_launch(void* const* d_in, const int* in_sizes, int n_in,
                              void* d_out, int out_size, void* d_ws, size_t ws_size,
                              hipStream_t stream) {
    const float* x  = (const float*)d_in[0];
    const float* wg = (const float*)d_in[1];
    const float* W1 = (const float*)d_in[2];
    const float* b1 = (const float*)d_in[3];
    const float* W2 = (const float*)d_in[4];
    const float* b2 = (const float*)d_in[5];

    char* ws = (char*)d_ws;
    int*    cnt  = (int*)ws;                          // 32 B
    float4* rec  = (float4*)(ws + 256);               // 256 KB
    uint2*  asg  = (uint2*)(ws + 262400);             // 896 KB
    u16*    xb   = (u16*)(ws + 1179904);              // 16 MB
    u16*    w1t  = (u16*)(ws + 17957120);             // 14.68 MB
    u16*    w2t  = (u16*)(ws + 32637184);             // 14.68 MB
    u16*    ybuf = (u16*)(ws + 47317248);             // 32 MB

    hipMemsetAsync(cnt, 0, 32, stream);
    k_transpose_cvt<<<dim3(64, 16, 7), 256, 0, stream>>>(W1, w1t, 512, 2048);
    k_transpose_cvt<<<dim3(16, 64, 7), 256, 0, stream>>>(W2, w2t, 2048, 512);
    k_gate<<<4096, 256, 0, stream>>>(x, wg, xb, cnt, asg, rec);
    k_expert<<<dim3(256, 7), 1024, 0, stream>>>(xb, w1t, w2t, b1, b2, cnt, asg, ybuf);
    k_final<<<8192, 256, 0, stream>>>(x, rec, ybuf, (float*)d_out);
}